// Round 7
// baseline (250.430 us; speedup 1.0000x reference)
//
#include <hip/hip_runtime.h>
#include <stdint.h>

#define BB 4
#define HH 256
#define WW 256
#define CC 128
#define NN 32
#define NPIX (HH*WW)            // 65536
#define RANK 52428u             // 0-based order-stat index: 0.8*(65536-1) exactly
#define TOTAL_PAIRS 1984.0f     // B * N*(N-1)/2

// workspace byte offsets
// sm (u32): [12+b]=thr_key(bits)
#define OFF_SM      0                         // 4 KiB
#define OFF_H       4096                      // BB*65536 u32 = 1 MiB
#define OFF_GSPLIT  (OFF_H + BB*65536*4)      // BB*12288 shorts = 96 KiB
#define OFF_GN      (OFF_GSPLIT + BB*12288*2) // BB*NN floats (pad 4 KiB)
#define OFF_KEYS    (OFF_GN + 4096)           // BB*NPIX u32 = 1 MiB
#define OFF_P       (OFF_KEYS + BB*NPIX*4)    // BB*NPIX i32 = 1 MiB

typedef __attribute__((ext_vector_type(8))) short short8;
typedef __attribute__((ext_vector_type(4))) float f32x4;

// 3-way bf16 split via truncation; residual <= 2^-24 |f| (absmax 0 in rounds 3-6).
__device__ __forceinline__ void split3(float f, short &hi, short &mid, short &lo) {
    uint32_t u  = __float_as_uint(f);
    uint32_t hb = u & 0xffff0000u;
    hi = (short)(hb >> 16);
    float r1 = f - __uint_as_float(hb);
    uint32_t mb = __float_as_uint(r1) & 0xffff0000u;
    mid = (short)(mb >> 16);
    float r2 = r1 - __uint_as_float(mb);
    lo = (short)(__float_as_uint(r2) >> 16);
}

// quantized bin: monotone nondecreasing in d2 (x128 exact pow2 scale) -> exact select.
__device__ __forceinline__ uint32_t qbin_of(uint32_t keybits) {
    float f = __uint_as_float(keybits);
    return (uint32_t)fminf(f * 128.0f, 65535.0f);
}

// ---------------- K0: gather center features -> split B-fragments + |g|^2; zero h/sm ----
__global__ void k_gather(const float* __restrict__ feat, const int* __restrict__ centers,
                         short* __restrict__ gsplit, float* __restrict__ gnorm,
                         uint32_t* __restrict__ h, uint32_t* __restrict__ sm) {
    int g = blockIdx.x;           // 128 blocks
    int b = g >> 5, n = g & 31;
    int c = threadIdx.x;          // 128 threads

    {   // zero histogram (1 MiB) + sm
        uint4* h4 = (uint4*)h;
        int zi = g*128 + c;
        #pragma unroll
        for (int i = 0; i < 4; i++) h4[zi + i*16384] = make_uint4(0,0,0,0);
        if (g == 0 && c < 64) sm[c] = 0;
    }

    int cy = centers[(b*NN + n)*2 + 0];
    int cx = centers[(b*NN + n)*2 + 1];
    float v = feat[((size_t)(b << 16) + cy*WW + cx)*CC + c];
    short hi, mid, lo; split3(v, hi, mid, lo);
    int tt = n >> 4, kk = c >> 5, q = (c & 31) >> 3, j = c & 7;
    int lane = q*16 + (n & 15);
    size_t base = (size_t)b*12288 + (size_t)(tt*4 + kk)*512 + lane*8 + j;
    gsplit[base]        = hi;
    gsplit[base + 4096] = mid;
    gsplit[base + 8192] = lo;

    __shared__ float s[128];
    s[c] = v*v;
    __syncthreads();
    for (int off = 64; off > 0; off >>= 1) {
        if (c < off) s[c] += s[c+off];
        __syncthreads();
    }
    if (c == 0) gnorm[b*NN + n] = s[0];
}

// ---------------- K1: MFMA min squared distance -> keys + fused quantized histogram ------
// block = 256 threads = 4 waves; each wave loops 4 tiles of 16 pixels => 256 px/block.
__global__ __launch_bounds__(256) void k_d2mfma(const float* __restrict__ feat,
        const short* __restrict__ gsplit, const float* __restrict__ gnorm,
        uint32_t* __restrict__ keys, uint32_t* __restrict__ h) {
    __shared__ short gB[12288];   // 24 KiB: [s][t*4+kk][lane][8]
    int b = blockIdx.y;

    {   // stage pre-split G fragments once per block (coalesced 1536 uint4)
        const uint4* src = (const uint4*)(gsplit + (size_t)b*12288);
        uint4* dst = (uint4*)gB;
        #pragma unroll
        for (int i = 0; i < 6; i++) dst[threadIdx.x + i*256] = src[threadIdx.x + i*256];
    }
    __syncthreads();

    int wv = threadIdx.x >> 6, L = threadIdx.x & 63;
    int m = L & 15, q = L >> 4;
    float gn0 = gnorm[b*NN + m];
    float gn1 = gnorm[b*NN + 16 + m];

    for (int it = 0; it < 4; it++) {
        int p0 = blockIdx.x*256 + (wv*4 + it)*16;
        const float* fp = feat + ((size_t)(b << 16) + p0 + m)*CC + q*8;

        f32x4 acc[2] = {{0.f,0.f,0.f,0.f},{0.f,0.f,0.f,0.f}};
        float fn = 0.f;

        #pragma unroll
        for (int kk = 0; kk < 4; kk++) {
            float4 fa = *(const float4*)(fp + kk*32);
            float4 fb = *(const float4*)(fp + kk*32 + 4);
            float fs[8] = {fa.x,fa.y,fa.z,fa.w,fb.x,fb.y,fb.z,fb.w};
            short8 ahi, amid, alo;
            #pragma unroll
            for (int j = 0; j < 8; j++) {
                float f = fs[j];
                fn = fmaf(f, f, fn);
                short hh, md, lw; split3(f, hh, md, lw);
                ahi[j] = hh; amid[j] = md; alo[j] = lw;
            }
            #pragma unroll
            for (int t = 0; t < 2; t++) {
                int off = (t*4 + kk)*512 + L*8;
                short8 bhi = *(const short8*)&gB[off];
                short8 bmd = *(const short8*)&gB[off + 4096];
                short8 blo = *(const short8*)&gB[off + 8192];
                acc[t] = __builtin_amdgcn_mfma_f32_16x16x32_bf16(ahi,  bhi, acc[t], 0,0,0);
                acc[t] = __builtin_amdgcn_mfma_f32_16x16x32_bf16(ahi,  bmd, acc[t], 0,0,0);
                acc[t] = __builtin_amdgcn_mfma_f32_16x16x32_bf16(amid, bhi, acc[t], 0,0,0);
                acc[t] = __builtin_amdgcn_mfma_f32_16x16x32_bf16(ahi,  blo, acc[t], 0,0,0);
                acc[t] = __builtin_amdgcn_mfma_f32_16x16x32_bf16(amid, bmd, acc[t], 0,0,0);
                acc[t] = __builtin_amdgcn_mfma_f32_16x16x32_bf16(alo,  bhi, acc[t], 0,0,0);
            }
        }

        fn += __shfl_xor(fn, 16);
        fn += __shfl_xor(fn, 32);

        // C layout: col(n) = L&15, row(pixel) = q*4 + reg
        float vmin[4];
        #pragma unroll
        for (int r = 0; r < 4; r++) {
            float fnr = __shfl(fn, q*4 + r);
            float d0 = fnr + gn0 - 2.f*acc[0][r];
            float d1 = fnr + gn1 - 2.f*acc[1][r];
            float v = fminf(d0, d1);
            v = fminf(v, __shfl_xor(v, 1));
            v = fminf(v, __shfl_xor(v, 2));
            v = fminf(v, __shfl_xor(v, 4));
            v = fminf(v, __shfl_xor(v, 8));
            vmin[r] = v;
        }
        if (m < 4) {
            float v = (m==0) ? vmin[0] : (m==1) ? vmin[1] : (m==2) ? vmin[2] : vmin[3];
            if (!(v > 0.f)) v = 0.f;
            uint32_t key = __float_as_uint(v);
            keys[(size_t)(b << 16) + p0 + q*4 + m] = key;
            atomicAdd(&h[(b << 16) + qbin_of(key)], 1u);   // spread bins: low contention
        }
    }
}

// ---------------- K2: fused select: histogram scan + collect + exact rank -> thr ----------
__global__ __launch_bounds__(1024) void k_selthr(const uint32_t* __restrict__ h,
        const uint32_t* __restrict__ keys, uint32_t* __restrict__ sm) {
    int b = blockIdx.x, t = threadIdx.x;   // 4 blocks x 1024
    __shared__ uint32_t wsum[16];
    __shared__ uint32_t sT, sR2, scnt;
    __shared__ uint32_t cand[4096];

    // 1) segment sum: 64 bins/thread
    const uint4* h4 = (const uint4*)(h + (b << 16) + t*64);
    uint32_t s = 0;
    #pragma unroll
    for (int i = 0; i < 16; i++) { uint4 v = h4[i]; s += v.x + v.y + v.z + v.w; }

    // 2) exclusive prefix over 1024 via wave-shuffle scan + cross-wave fix
    int lane = t & 63, w = t >> 6;
    uint32_t inc = s;
    #pragma unroll
    for (int off = 1; off < 64; off <<= 1) {
        uint32_t nb = __shfl_up((int)inc, off);
        if (lane >= off) inc += nb;
    }
    if (lane == 63) wsum[w] = inc;
    if (t == 0) scnt = 0;
    __syncthreads();
    if (t < 16) {
        uint32_t v = wsum[t];
        #pragma unroll
        for (int off = 1; off < 16; off <<= 1) {
            uint32_t nb = __shfl_up((int)v, off);
            if (t >= off) v += nb;
        }
        wsum[t] = v;   // inclusive wave-sum scan
    }
    __syncthreads();
    uint32_t base = (w == 0) ? 0u : wsum[w-1];
    uint32_t pre = base + inc - s;   // exclusive prefix of thread t's segment

    uint32_t r = RANK;
    if (pre <= r && r < pre + s) {
        uint32_t c = pre;
        const uint32_t* hb = h + (b << 16) + t*64;
        for (int i = 0; i < 64; i++) {
            uint32_t hc = hb[i];
            if (r < c + hc) { sT = (uint32_t)(t*64 + i); sR2 = r - c; break; }
            c += hc;
        }
    }
    __syncthreads();
    uint32_t T = sT, r2 = sR2;

    // 3) collect candidate keys in bin T into LDS (~10 expected)
    const uint32_t* kb = keys + (b << 16);
    for (int i = t; i < NPIX; i += 1024) {
        uint32_t k = kb[i];
        if (qbin_of(k) == T) {
            uint32_t pos = atomicAdd(&scnt, 1u);
            if (pos < 4096u) cand[pos] = k;
        }
    }
    __syncthreads();
    uint32_t K = scnt; if (K > 4096u) K = 4096u;

    // 4) exact rank among candidates (duplicate-safe)
    for (uint32_t i = t; i < K; i += 1024) {
        uint32_t v = cand[i];
        uint32_t less = 0, eq = 0;
        for (uint32_t j = 0; j < K; j++) { uint32_t x = cand[j]; less += (x < v); eq += (x == v); }
        if (less <= r2 && r2 < less + eq) sm[12 + b] = v;   // all writers agree
    }
}

// ---------------- K3: init parents as row-run starts (horizontal unions become free) -----
__global__ __launch_bounds__(256) void k_initrun(const uint32_t* __restrict__ keys,
        const uint32_t* __restrict__ sm, int* __restrict__ P) {
    int b = blockIdx.y;
    int row = blockIdx.x, x = threadIdx.x;   // block = one image row
    int p = row*256 + x;
    uint32_t thr = sm[12 + b];
    bool msk = keys[(b << 16) + p] >= thr;

    // inclusive max-scan of z[x] = msk ? -1 : x  => last unmasked index <= x
    __shared__ int wmax[4];
    int lane = x & 63, w = x >> 6;
    int v = msk ? -1 : x;
    #pragma unroll
    for (int off = 1; off < 64; off <<= 1) {
        int nb = __shfl_up(v, off);
        if (lane >= off) v = max(v, nb);
    }
    if (lane == 63) wmax[w] = v;
    __syncthreads();
    int acc = v;
    for (int i = 0; i < w; i++) acc = max(acc, wmax[i]);
    // run start for masked x = acc+1
    P[(b << 16) + p] = msk ? (row*256 + acc + 1) : -1;
}

// ---------------- K4: union-find CCL — vertical/diagonal merges only ----------------
__device__ __forceinline__ int uf_find(int* P, int x) {
    while (true) {
        int p = P[x];
        if (p == x) return x;
        int gp = P[p];
        if (gp != p) P[x] = gp;   // path halving (benign race)
        x = gp;
    }
}
__device__ __forceinline__ void uf_unite(int* P, int a, int b) {
    while (true) {
        a = uf_find(P, a);
        b = uf_find(P, b);
        if (a == b) return;
        if (a > b) { int t = a; a = b; b = t; }
        int old = atomicCAS(&P[b], b, a);   // device-scope
        if (old == b) return;
        b = old;
    }
}
__global__ __launch_bounds__(256) void k_union(int* __restrict__ Pg) {
    int b = blockIdx.y;
    int p = blockIdx.x*256 + threadIdx.x;
    int* P = Pg + (b << 16);
    if (P[p] == -1) return;
    int y = p >> 8, x = p & 255;
    if (y == 0) return;
    // upper-row overlap {x-1,x,x+1}: consecutive masked pixels there share a run,
    // so at most 2 distinct runs need uniting.
    bool ul = (x > 0)   && P[p-WW-1] != -1;
    bool uu =              P[p-WW]   != -1;
    bool ur = (x < 255) && P[p-WW+1] != -1;
    if (ul)        uf_unite(P, p, p-WW-1);
    if (uu && !ul) uf_unite(P, p, p-WW);
    if (ur && !uu) uf_unite(P, p, p-WW+1);
}

// ---------------- K5: merged pairs at centers + output ----------------
__global__ void k_pairs_fin(const int* __restrict__ centers, int* __restrict__ Pg,
                            float* __restrict__ out) {
    __shared__ int ids[BB*NN];
    __shared__ int total;
    int t = threadIdx.x;
    if (t == 0) total = 0;
    __syncthreads();
    if (t < BB*NN) {
        int b = t >> 5;
        int cy = centers[t*2 + 0];
        int cx = centers[t*2 + 1];
        int p = cy*WW + cx;
        const int* P = Pg + (b << 16);
        int id = P[p];
        if (id != -1) {
            int x = p;
            while (true) { int q = P[x]; if (q == x) break; x = q; }
            id = x;
        }
        ids[t] = id;
    }
    __syncthreads();
    int cnt = 0;
    if (t < BB*NN) {
        int b = t >> 5, n = t & 31;
        int id = ids[t];
        if (id != -1) for (int j = n+1; j < NN; j++) cnt += (ids[b*NN + j] == id);
    }
    if (cnt) atomicAdd(&total, cnt);
    __syncthreads();
    if (t == 0) out[0] = (float)total / TOTAL_PAIRS;
}

extern "C" void kernel_launch(void* const* d_in, const int* in_sizes, int n_in,
                              void* d_out, int out_size, void* d_ws, size_t ws_size,
                              hipStream_t stream) {
    const float* feat  = (const float*)d_in[0];
    const int* centers = (const int*)d_in[1];
    float* out         = (float*)d_out;
    char* ws           = (char*)d_ws;

    uint32_t* sm     = (uint32_t*)(ws + OFF_SM);
    uint32_t* h      = (uint32_t*)(ws + OFF_H);
    short*    gsplit = (short*)(ws + OFF_GSPLIT);
    float*    gnorm  = (float*)(ws + OFF_GN);
    uint32_t* keys   = (uint32_t*)(ws + OFF_KEYS);
    int*      Pg     = (int*)(ws + OFF_P);

    dim3 gridPix(NPIX/256, BB);
    dim3 gridMM(NPIX/256, BB);   // 256 px/block

    k_gather    <<<BB*NN, CC, 0, stream>>>(feat, centers, gsplit, gnorm, h, sm);
    k_d2mfma    <<<gridMM, 256, 0, stream>>>(feat, gsplit, gnorm, keys, h);
    k_selthr    <<<BB, 1024, 0, stream>>>(h, keys, sm);
    k_initrun   <<<gridPix, 256, 0, stream>>>(keys, sm, Pg);
    k_union     <<<gridPix, 256, 0, stream>>>(Pg);
    k_pairs_fin <<<1, 256, 0, stream>>>(centers, Pg, out);
}

// Round 8
// 232.343 us; speedup vs baseline: 1.0778x; 1.0778x over previous
//
#include <hip/hip_runtime.h>
#include <stdint.h>

#define BB 4
#define HH 256
#define WW 256
#define CC 128
#define NN 32
#define NPIX (HH*WW)            // 65536
#define RANK 52428u             // 0-based order-stat index: 0.8*(65536-1) exactly
#define TOTAL_PAIRS 1984.0f     // B * N*(N-1)/2

// workspace byte offsets; sm (u32): [12+b]=thr_key(bits). No zeroing needed anywhere.
#define OFF_SM      0                         // 4 KiB
#define OFF_KEYS    4096                      // BB*NPIX u32 = 1 MiB
#define OFF_P       (OFF_KEYS + BB*NPIX*4)    // BB*NPIX i32 = 1 MiB

typedef __attribute__((ext_vector_type(8))) short short8;
typedef __attribute__((ext_vector_type(4))) float f32x4;

// 3-way bf16 split via truncation; residual <= 2^-24 |f| (absmax 0 in rounds 3-7).
__device__ __forceinline__ void split3(float f, short &hi, short &mid, short &lo) {
    uint32_t u  = __float_as_uint(f);
    uint32_t hb = u & 0xffff0000u;
    hi = (short)(hb >> 16);
    float r1 = f - __uint_as_float(hb);
    uint32_t mb = __float_as_uint(r1) & 0xffff0000u;
    mid = (short)(mb >> 16);
    float r2 = r1 - __uint_as_float(mb);
    lo = (short)(__float_as_uint(r2) >> 16);
}

// quantized bin: monotone nondecreasing in d2 (x128 exact pow2 scale) -> exact select.
__device__ __forceinline__ uint32_t qbin_of(uint32_t keybits) {
    float f = __uint_as_float(keybits);
    return (uint32_t)fminf(f * 128.0f, 65535.0f);
}

// ---------------- K0: MFMA min squared distance -> keys (gather inlined, no atomics) -----
// block = 256 threads = 4 waves; each wave loops 4 tiles of 16 pixels => 256 px/block.
__global__ __launch_bounds__(256) void k_d2mfma(const float* __restrict__ feat,
        const int* __restrict__ centers, uint32_t* __restrict__ keys) {
    __shared__ short gB[12288];      // 24 KiB: [s][tt*4+kk][lane][8]
    __shared__ float gpart[32][8];
    __shared__ float gnormL[32];
    int b = blockIdx.y;
    int tid = threadIdx.x;

    // ---- inline gather: thread (n = tid&31, j0 = tid>>5) owns center n, cols [j0*16,+16)
    {
        int n = tid & 31, j0 = tid >> 5;
        int cy = centers[(b*NN + n)*2 + 0];
        int cx = centers[(b*NN + n)*2 + 1];
        const float* gp = feat + ((size_t)(b << 16) + cy*WW + cx)*CC + j0*16;
        int tt = n >> 4, lane16 = n & 15, kk = j0 >> 1, qbase = (j0 & 1)*2;
        float ss = 0.f;
        #pragma unroll
        for (int hh = 0; hh < 2; hh++) {         // two 8-col halves -> q = qbase+hh
            short8 vhi, vmid, vlo;
            #pragma unroll
            for (int u = 0; u < 8; u++) {
                float f = gp[hh*8 + u];
                ss = fmaf(f, f, ss);
                short a, bm, c; split3(f, a, bm, c);
                vhi[u] = a; vmid[u] = bm; vlo[u] = c;
            }
            int lane = (qbase + hh)*16 + lane16;
            int off = (tt*4 + kk)*512 + lane*8;  // shorts; 16B-aligned contiguous
            *(short8*)&gB[off]        = vhi;
            *(short8*)&gB[off + 4096] = vmid;
            *(short8*)&gB[off + 8192] = vlo;
        }
        gpart[n][j0] = ss;
    }
    __syncthreads();
    if (tid < 32) {
        float s = 0.f;
        #pragma unroll
        for (int j = 0; j < 8; j++) s += gpart[tid][j];
        gnormL[tid] = s;
    }
    __syncthreads();

    int wv = tid >> 6, L = tid & 63;
    int m = L & 15, q = L >> 4;
    float gn0 = gnormL[m];
    float gn1 = gnormL[16 + m];

    for (int it = 0; it < 4; it++) {
        int p0 = blockIdx.x*256 + (wv*4 + it)*16;
        const float* fp = feat + ((size_t)(b << 16) + p0 + m)*CC + q*8;

        f32x4 acc[2] = {{0.f,0.f,0.f,0.f},{0.f,0.f,0.f,0.f}};
        float fn = 0.f;

        #pragma unroll
        for (int kk = 0; kk < 4; kk++) {
            float4 fa = *(const float4*)(fp + kk*32);
            float4 fb = *(const float4*)(fp + kk*32 + 4);
            float fs[8] = {fa.x,fa.y,fa.z,fa.w,fb.x,fb.y,fb.z,fb.w};
            short8 ahi, amid, alo;
            #pragma unroll
            for (int j = 0; j < 8; j++) {
                float f = fs[j];
                fn = fmaf(f, f, fn);
                short hh, md, lw; split3(f, hh, md, lw);
                ahi[j] = hh; amid[j] = md; alo[j] = lw;
            }
            #pragma unroll
            for (int t = 0; t < 2; t++) {
                int off = (t*4 + kk)*512 + L*8;
                short8 bhi = *(const short8*)&gB[off];
                short8 bmd = *(const short8*)&gB[off + 4096];
                short8 blo = *(const short8*)&gB[off + 8192];
                // 6 significant split products
                acc[t] = __builtin_amdgcn_mfma_f32_16x16x32_bf16(ahi,  bhi, acc[t], 0,0,0);
                acc[t] = __builtin_amdgcn_mfma_f32_16x16x32_bf16(ahi,  bmd, acc[t], 0,0,0);
                acc[t] = __builtin_amdgcn_mfma_f32_16x16x32_bf16(amid, bhi, acc[t], 0,0,0);
                acc[t] = __builtin_amdgcn_mfma_f32_16x16x32_bf16(ahi,  blo, acc[t], 0,0,0);
                acc[t] = __builtin_amdgcn_mfma_f32_16x16x32_bf16(amid, bmd, acc[t], 0,0,0);
                acc[t] = __builtin_amdgcn_mfma_f32_16x16x32_bf16(alo,  bhi, acc[t], 0,0,0);
            }
        }

        fn += __shfl_xor(fn, 16);
        fn += __shfl_xor(fn, 32);

        // C layout: col(n) = L&15, row(pixel) = q*4 + reg
        float vmin[4];
        #pragma unroll
        for (int r = 0; r < 4; r++) {
            float fnr = __shfl(fn, q*4 + r);
            float d0 = fnr + gn0 - 2.f*acc[0][r];
            float d1 = fnr + gn1 - 2.f*acc[1][r];
            float v = fminf(d0, d1);
            v = fminf(v, __shfl_xor(v, 1));
            v = fminf(v, __shfl_xor(v, 2));
            v = fminf(v, __shfl_xor(v, 4));
            v = fminf(v, __shfl_xor(v, 8));
            vmin[r] = v;
        }
        if (m < 4) {
            float v = (m==0) ? vmin[0] : (m==1) ? vmin[1] : (m==2) ? vmin[2] : vmin[3];
            if (!(v > 0.f)) v = 0.f;     // clamp negatives and -0.0
            keys[(size_t)(b << 16) + p0 + q*4 + m] = __float_as_uint(v);
        }
    }
}

// ---------------- K1: 3-scan LDS radix select -> exact threshold key bits ----------------
// 4 blocks x 1024; keys are L2-resident (256 KiB/batch).
__global__ __launch_bounds__(1024) void k_selthr(const uint32_t* __restrict__ keys,
                                                 uint32_t* __restrict__ sm) {
    int b = blockIdx.x, t = threadIdx.x;
    __shared__ uint32_t h1[1024];
    __shared__ uint32_t h2[64];
    __shared__ uint32_t wsum[16];
    __shared__ uint32_t sT1, sR1, sT, sR2, scnt;
    __shared__ uint32_t cand[8192];
    const uint4* kb = (const uint4*)(keys + (b << 16));

    h1[t] = 0;
    if (t < 64) h2[t] = 0;
    if (t == 0) scnt = 0;
    __syncthreads();

    // scan 1: coarse hist of qbin>>6 (1024 bins)
    for (int i = t; i < NPIX/4; i += 1024) {
        uint4 k = kb[i];
        atomicAdd(&h1[qbin_of(k.x) >> 6], 1u);
        atomicAdd(&h1[qbin_of(k.y) >> 6], 1u);
        atomicAdd(&h1[qbin_of(k.z) >> 6], 1u);
        atomicAdd(&h1[qbin_of(k.w) >> 6], 1u);
    }
    __syncthreads();

    // level-1 select: prefix over 1024 bins (wave scan + cross-wave fix)
    int lane = t & 63, w = t >> 6;
    uint32_t s = h1[t];
    uint32_t inc = s;
    #pragma unroll
    for (int off = 1; off < 64; off <<= 1) {
        uint32_t nb = __shfl_up((int)inc, off);
        if (lane >= off) inc += nb;
    }
    if (lane == 63) wsum[w] = inc;
    __syncthreads();
    if (t < 16) {
        uint32_t v = wsum[t];
        #pragma unroll
        for (int off = 1; off < 16; off <<= 1) {
            uint32_t nb = __shfl_up((int)v, off);
            if (t >= off) v += nb;
        }
        wsum[t] = v;
    }
    __syncthreads();
    uint32_t pre = ((w == 0) ? 0u : wsum[w-1]) + inc - s;
    if (pre <= RANK && RANK < pre + s) { sT1 = (uint32_t)t; sR1 = RANK - pre; }
    __syncthreads();
    uint32_t T1 = sT1, r1 = sR1;

    // scan 2: 64-bin hist of qbin&63 among qbin>>6 == T1
    for (int i = t; i < NPIX/4; i += 1024) {
        uint4 k = kb[i];
        uint32_t q0 = qbin_of(k.x); if ((q0 >> 6) == T1) atomicAdd(&h2[q0 & 63u], 1u);
        uint32_t q1 = qbin_of(k.y); if ((q1 >> 6) == T1) atomicAdd(&h2[q1 & 63u], 1u);
        uint32_t q2 = qbin_of(k.z); if ((q2 >> 6) == T1) atomicAdd(&h2[q2 & 63u], 1u);
        uint32_t q3 = qbin_of(k.w); if ((q3 >> 6) == T1) atomicAdd(&h2[q3 & 63u], 1u);
    }
    __syncthreads();
    if (t < 64) {
        uint32_t s2 = h2[t];
        uint32_t inc2 = s2;
        #pragma unroll
        for (int off = 1; off < 64; off <<= 1) {
            uint32_t nb = __shfl_up((int)inc2, off);
            if (t >= off) inc2 += nb;
        }
        uint32_t pre2 = inc2 - s2;
        if (pre2 <= r1 && r1 < pre2 + s2) { sT = (T1 << 6) | (uint32_t)t; sR2 = r1 - pre2; }
    }
    __syncthreads();
    uint32_t T = sT, r2 = sR2;

    // scan 3: collect keys with qbin == T (~10 expected)
    for (int i = t; i < NPIX/4; i += 1024) {
        uint4 k = kb[i];
        if (qbin_of(k.x) == T) { uint32_t p = atomicAdd(&scnt, 1u); if (p < 8192u) cand[p] = k.x; }
        if (qbin_of(k.y) == T) { uint32_t p = atomicAdd(&scnt, 1u); if (p < 8192u) cand[p] = k.y; }
        if (qbin_of(k.z) == T) { uint32_t p = atomicAdd(&scnt, 1u); if (p < 8192u) cand[p] = k.z; }
        if (qbin_of(k.w) == T) { uint32_t p = atomicAdd(&scnt, 1u); if (p < 8192u) cand[p] = k.w; }
    }
    __syncthreads();
    uint32_t K = scnt; if (K > 8192u) K = 8192u;

    // exact rank among candidates (duplicate-safe)
    for (uint32_t i = t; i < K; i += 1024) {
        uint32_t v = cand[i];
        uint32_t less = 0, eq = 0;
        for (uint32_t j = 0; j < K; j++) { uint32_t x = cand[j]; less += (x < v); eq += (x == v); }
        if (less <= r2 && r2 < less + eq) sm[12 + b] = v;   // all writers agree
    }
}

// ---------------- K2: init parents as row-run starts (horizontal unions free) ----------
__global__ __launch_bounds__(256) void k_initrun(const uint32_t* __restrict__ keys,
        const uint32_t* __restrict__ sm, int* __restrict__ P) {
    int b = blockIdx.y;
    int row = blockIdx.x, x = threadIdx.x;   // block = one image row
    int p = row*256 + x;
    uint32_t thr = sm[12 + b];
    bool msk = keys[(b << 16) + p] >= thr;

    __shared__ int wmax[4];
    int lane = x & 63, w = x >> 6;
    int v = msk ? -1 : x;
    #pragma unroll
    for (int off = 1; off < 64; off <<= 1) {
        int nb = __shfl_up(v, off);
        if (lane >= off) v = max(v, nb);
    }
    if (lane == 63) wmax[w] = v;
    __syncthreads();
    int acc = v;
    for (int i = 0; i < w; i++) acc = max(acc, wmax[i]);
    P[(b << 16) + p] = msk ? (row*256 + acc + 1) : -1;
}

// ---------------- K3: union-find CCL — vertical/diagonal merges only ----------------
__device__ __forceinline__ int uf_find(int* P, int x) {
    while (true) {
        int p = P[x];
        if (p == x) return x;
        int gp = P[p];
        if (gp != p) P[x] = gp;   // path halving (benign race)
        x = gp;
    }
}
__device__ __forceinline__ void uf_unite(int* P, int a, int b) {
    while (true) {
        a = uf_find(P, a);
        b = uf_find(P, b);
        if (a == b) return;
        if (a > b) { int t = a; a = b; b = t; }
        int old = atomicCAS(&P[b], b, a);   // device-scope
        if (old == b) return;
        b = old;
    }
}
__global__ __launch_bounds__(256) void k_union(int* __restrict__ Pg) {
    int b = blockIdx.y;
    int p = blockIdx.x*256 + threadIdx.x;
    int* P = Pg + (b << 16);
    if (P[p] == -1) return;
    int y = p >> 8, x = p & 255;
    if (y == 0) return;
    bool ul = (x > 0)   && P[p-WW-1] != -1;
    bool uu =              P[p-WW]   != -1;
    bool ur = (x < 255) && P[p-WW+1] != -1;
    if (ul)        uf_unite(P, p, p-WW-1);
    if (uu && !ul) uf_unite(P, p, p-WW);
    if (ur && !uu) uf_unite(P, p, p-WW+1);
}

// ---------------- K4: merged pairs at centers + output ----------------
__global__ void k_pairs_fin(const int* __restrict__ centers, int* __restrict__ Pg,
                            float* __restrict__ out) {
    __shared__ int ids[BB*NN];
    __shared__ int total;
    int t = threadIdx.x;
    if (t == 0) total = 0;
    __syncthreads();
    if (t < BB*NN) {
        int b = t >> 5;
        int cy = centers[t*2 + 0];
        int cx = centers[t*2 + 1];
        int p = cy*WW + cx;
        const int* P = Pg + (b << 16);
        int id = P[p];
        if (id != -1) {
            int x = p;
            while (true) { int q = P[x]; if (q == x) break; x = q; }
            id = x;
        }
        ids[t] = id;
    }
    __syncthreads();
    int cnt = 0;
    if (t < BB*NN) {
        int b = t >> 5, n = t & 31;
        int id = ids[t];
        if (id != -1) for (int j = n+1; j < NN; j++) cnt += (ids[b*NN + j] == id);
    }
    if (cnt) atomicAdd(&total, cnt);
    __syncthreads();
    if (t == 0) out[0] = (float)total / TOTAL_PAIRS;
}

extern "C" void kernel_launch(void* const* d_in, const int* in_sizes, int n_in,
                              void* d_out, int out_size, void* d_ws, size_t ws_size,
                              hipStream_t stream) {
    const float* feat  = (const float*)d_in[0];
    const int* centers = (const int*)d_in[1];
    float* out         = (float*)d_out;
    char* ws           = (char*)d_ws;

    uint32_t* sm   = (uint32_t*)(ws + OFF_SM);
    uint32_t* keys = (uint32_t*)(ws + OFF_KEYS);
    int*      Pg   = (int*)(ws + OFF_P);

    dim3 gridPix(NPIX/256, BB);

    k_d2mfma    <<<gridPix, 256, 0, stream>>>(feat, centers, keys);
    k_selthr    <<<BB, 1024, 0, stream>>>(keys, sm);
    k_initrun   <<<gridPix, 256, 0, stream>>>(keys, sm, Pg);
    k_union     <<<gridPix, 256, 0, stream>>>(Pg);
    k_pairs_fin <<<1, 256, 0, stream>>>(centers, Pg, out);
}